// Round 1
// baseline (137.364 us; speedup 1.0000x reference)
//
#include <hip/hip_runtime.h>
#include <math.h>

constexpr int NPTS  = 16384;   // P == G == 16384 for this problem
constexpr int BLOCK = 256;
constexpr int SPLIT = 16;      // B-dimension split for parallelism
constexpr int CHUNK = NPTS / SPLIT;  // 1024 points = 16 KB LDS

// ---------------------------------------------------------------------------
// Pack (x,y,z) -> float4(x,y,z,||p||^2), init min arrays to +inf, zero accums.
// Must run every call: ws is re-poisoned to 0xAA before each timed launch.
// ---------------------------------------------------------------------------
__global__ __launch_bounds__(BLOCK) void pack_init_kernel(
    const float* __restrict__ pred, const float* __restrict__ gt,
    float4* __restrict__ packP, float4* __restrict__ packG,
    unsigned int* __restrict__ minP, unsigned int* __restrict__ minG,
    float* __restrict__ accum)
{
    int i = blockIdx.x * BLOCK + threadIdx.x;
    if (i < NPTS) {
        float x = pred[3*i], y = pred[3*i+1], z = pred[3*i+2];
        packP[i] = make_float4(x, y, z, fmaf(x,x, fmaf(y,y, z*z)));
        x = gt[3*i]; y = gt[3*i+1]; z = gt[3*i+2];
        packG[i] = make_float4(x, y, z, fmaf(x,x, fmaf(y,y, z*z)));
        minP[i] = 0x7F800000u;   // +inf bits
        minG[i] = 0x7F800000u;
    }
    if (i < 4) accum[i] = 0.0f;
}

// ---------------------------------------------------------------------------
// For each point a in A, min over a CHUNK of B of (b2 - 2 a.b); a2 added at
// the end. atomicMin on uint bits is order-correct for non-negative floats.
// ---------------------------------------------------------------------------
__global__ __launch_bounds__(BLOCK) void min_dist_kernel(
    const float4* __restrict__ A,
    const float4* __restrict__ B,
    unsigned int* __restrict__ out_min_bits)
{
    __shared__ float4 sB[CHUNK];

    const int i  = blockIdx.x * BLOCK + threadIdx.x;
    const int b0 = blockIdx.y * CHUNK;

    const float4 a = A[i];

    // Stage the whole chunk once (coalesced float4 loads).
    for (int k = threadIdx.x; k < CHUNK; k += BLOCK)
        sB[k] = B[b0 + k];
    __syncthreads();

    // 4 independent min accumulators to break the fmin dependency chain.
    float m0 = INFINITY, m1 = INFINITY, m2 = INFINITY, m3 = INFINITY;
    #pragma unroll 2
    for (int j = 0; j < CHUNK; j += 4) {
        float4 b0v = sB[j+0];
        float4 b1v = sB[j+1];
        float4 b2v = sB[j+2];
        float4 b3v = sB[j+3];
        float t0 = fmaf(a.x, b0v.x, fmaf(a.y, b0v.y, a.z * b0v.z));
        float t1 = fmaf(a.x, b1v.x, fmaf(a.y, b1v.y, a.z * b1v.z));
        float t2 = fmaf(a.x, b2v.x, fmaf(a.y, b2v.y, a.z * b2v.z));
        float t3 = fmaf(a.x, b3v.x, fmaf(a.y, b3v.y, a.z * b3v.z));
        m0 = fminf(m0, fmaf(-2.0f, t0, b0v.w));
        m1 = fminf(m1, fmaf(-2.0f, t1, b1v.w));
        m2 = fminf(m2, fmaf(-2.0f, t2, b2v.w));
        m3 = fminf(m3, fmaf(-2.0f, t3, b3v.w));
    }
    float m = fminf(fminf(m0, m1), fminf(m2, m3));
    float d = fmaxf(a.w + m, 0.0f);          // clamp commutes with min
    atomicMin(&out_min_bits[i], __float_as_uint(d));
}

// ---------------------------------------------------------------------------
// sum(w * min) and sum(w): wave shuffle reduce -> block reduce -> atomicAdd.
// ---------------------------------------------------------------------------
__global__ __launch_bounds__(BLOCK) void weighted_sum_kernel(
    const unsigned int* __restrict__ min_bits,
    const float* __restrict__ w,
    float* __restrict__ acc_num, float* __restrict__ acc_den)
{
    int i = blockIdx.x * BLOCK + threadIdx.x;
    float num = 0.0f, den = 0.0f;
    if (i < NPTS) {
        float mv = __uint_as_float(min_bits[i]);
        float wv = w[i];
        num = wv * mv;
        den = wv;
    }
    // wave64 reduce
    for (int off = 32; off > 0; off >>= 1) {
        num += __shfl_down(num, off);
        den += __shfl_down(den, off);
    }
    __shared__ float snum[BLOCK/64], sden[BLOCK/64];
    int wid = threadIdx.x >> 6, lane = threadIdx.x & 63;
    if (lane == 0) { snum[wid] = num; sden[wid] = den; }
    __syncthreads();
    if (threadIdx.x == 0) {
        float tn = 0.0f, td = 0.0f;
        #pragma unroll
        for (int k = 0; k < BLOCK/64; ++k) { tn += snum[k]; td += sden[k]; }
        atomicAdd(acc_num, tn);
        atomicAdd(acc_den, td);
    }
}

__global__ void finalize_kernel(const float* __restrict__ accum,
                                float* __restrict__ out)
{
    out[0] = accum[0] / fmaxf(accum[1], 1e-9f)
           + accum[2] / fmaxf(accum[3], 1e-9f);
}

// ---------------------------------------------------------------------------
extern "C" void kernel_launch(void* const* d_in, const int* in_sizes, int n_in,
                              void* d_out, int out_size, void* d_ws, size_t ws_size,
                              hipStream_t stream)
{
    const float* pred  = (const float*)d_in[0];   // (P,3)
    const float* gt    = (const float*)d_in[1];   // (G,3)
    const float* wpred = (const float*)d_in[2];   // (P,)
    const float* wgt   = (const float*)d_in[3];   // (G,)
    float* out = (float*)d_out;

    // ws layout: packP | packG | minP | minG | accum[4]
    float4* packP = (float4*)d_ws;
    float4* packG = packP + NPTS;
    unsigned int* minP = (unsigned int*)(packG + NPTS);
    unsigned int* minG = minP + NPTS;
    float* accum = (float*)(minG + NPTS);

    pack_init_kernel<<<(NPTS + BLOCK - 1) / BLOCK, BLOCK, 0, stream>>>(
        pred, gt, packP, packG, minP, minG, accum);

    dim3 grid(NPTS / BLOCK, SPLIT);
    // pred -> nearest gt
    min_dist_kernel<<<grid, BLOCK, 0, stream>>>(packP, packG, minP);
    // gt -> nearest pred
    min_dist_kernel<<<grid, BLOCK, 0, stream>>>(packG, packP, minG);

    weighted_sum_kernel<<<NPTS / BLOCK, BLOCK, 0, stream>>>(minP, wpred, &accum[0], &accum[1]);
    weighted_sum_kernel<<<NPTS / BLOCK, BLOCK, 0, stream>>>(minG, wgt,   &accum[2], &accum[3]);

    finalize_kernel<<<1, 1, 0, stream>>>(accum, out);
}

// Round 2
// 107.997 us; speedup vs baseline: 1.2719x; 1.2719x over previous
//
#include <hip/hip_runtime.h>
#include <math.h>

constexpr int NPTS  = 16384;        // P == G
constexpr int BLOCK = 256;
constexpr int T     = 8;            // A-points per thread (register tile)
constexpr int ABLK  = BLOCK * T;    // 2048 A-points per block
constexpr int XBLK  = NPTS / ABLK;  // 8 blocks along A
constexpr int SPLIT = 64;           // B splits
constexpr int CHUNK = NPTS / SPLIT; // 256 B-points = 4 KB LDS

// ---------------------------------------------------------------------------
// Pack (x,y,z) -> float4(-2x,-2y,-2z,||r||^2) for both clouds; init min
// arrays to +inf bits; zero the 4 accumulators. Runs every call (ws is
// re-poisoned to 0xAA before each timed launch).
// ---------------------------------------------------------------------------
__global__ __launch_bounds__(BLOCK) void pack_init_kernel(
    const float* __restrict__ pred, const float* __restrict__ gt,
    float4* __restrict__ packP, float4* __restrict__ packG,
    unsigned int* __restrict__ minP, unsigned int* __restrict__ minG,
    float* __restrict__ accum)
{
    int i = blockIdx.x * BLOCK + threadIdx.x;
    if (i < NPTS) {
        float x = pred[3*i], y = pred[3*i+1], z = pred[3*i+2];
        packP[i] = make_float4(-2.0f*x, -2.0f*y, -2.0f*z,
                               fmaf(x,x, fmaf(y,y, z*z)));
        x = gt[3*i]; y = gt[3*i+1]; z = gt[3*i+2];
        packG[i] = make_float4(-2.0f*x, -2.0f*y, -2.0f*z,
                               fmaf(x,x, fmaf(y,y, z*z)));
        minP[i] = 0x7F800000u;   // +inf
        minG[i] = 0x7F800000u;
    }
    if (i < 4) accum[i] = 0.0f;
}

// ---------------------------------------------------------------------------
// Fused both-direction min-distance. blockIdx.z picks direction.
// B is pre-scaled by -2 with ||b||^2 in .w, so per pair:
//   t = fma(ax, bx', fma(ay, by', fma(az, bz', b2)))   == b2 - 2 a.b
// and min3 folds two pairs per min op. a2 added once after the loop.
// A coords reconstructed from the -2-scaled pack (x = -0.5 * x').
// ---------------------------------------------------------------------------
__global__ __launch_bounds__(BLOCK) void min_dist_kernel(
    const float4* __restrict__ packP,
    const float4* __restrict__ packG,
    unsigned int* __restrict__ minP,
    unsigned int* __restrict__ minG)
{
    const float4* __restrict__ A;
    const float4* __restrict__ B;
    unsigned int* __restrict__ out;
    if (blockIdx.z == 0) { A = packP; B = packG; out = minP; }
    else                 { A = packG; B = packP; out = minG; }

    __shared__ float4 sB[CHUNK];

    const int t     = threadIdx.x;
    const int aBase = blockIdx.x * ABLK;
    const int b0    = blockIdx.y * CHUNK;

    // Stage B chunk: exactly one float4 per thread (coalesced).
    sB[t] = B[b0 + t];

    // Load 8 A-points (strided by BLOCK for coalescing), undo the -2 scale.
    float ax[T], ay[T], az[T], a2[T];
    #pragma unroll
    for (int k = 0; k < T; ++k) {
        float4 m = A[aBase + k * BLOCK + t];
        ax[k] = -0.5f * m.x;
        ay[k] = -0.5f * m.y;
        az[k] = -0.5f * m.z;
        a2[k] = m.w;
    }
    __syncthreads();

    float mn[T];
    #pragma unroll
    for (int k = 0; k < T; ++k) mn[k] = INFINITY;

    #pragma unroll 2
    for (int j = 0; j < CHUNK; j += 2) {
        float4 u = sB[j];
        float4 v = sB[j + 1];
        #pragma unroll
        for (int k = 0; k < T; ++k) {
            float d0 = fmaf(ax[k], u.x, fmaf(ay[k], u.y, fmaf(az[k], u.z, u.w)));
            float d1 = fmaf(ax[k], v.x, fmaf(ay[k], v.y, fmaf(az[k], v.z, v.w)));
            mn[k] = fminf(mn[k], fminf(d0, d1));   // -> v_min3_f32
        }
    }

    #pragma unroll
    for (int k = 0; k < T; ++k) {
        float d = fmaxf(a2[k] + mn[k], 0.0f);      // clamp commutes with min
        atomicMin(&out[aBase + k * BLOCK + t], __float_as_uint(d));
    }
}

// ---------------------------------------------------------------------------
// Fused weighted sums: blockIdx.y picks (minP,w_pred)->accum[0:2] or
// (minG,w_gt)->accum[2:4]. Wave shuffle -> LDS -> one atomicAdd pair/block.
// ---------------------------------------------------------------------------
__global__ __launch_bounds__(BLOCK) void weighted_sum_kernel(
    const unsigned int* __restrict__ minP,
    const unsigned int* __restrict__ minG,
    const float* __restrict__ wpred,
    const float* __restrict__ wgt,
    float* __restrict__ accum)
{
    const unsigned int* mb = (blockIdx.y == 0) ? minP : minG;
    const float*        w  = (blockIdx.y == 0) ? wpred : wgt;
    float* acc = accum + 2 * blockIdx.y;

    int i = blockIdx.x * BLOCK + threadIdx.x;
    float num = 0.0f, den = 0.0f;
    if (i < NPTS) {
        float mv = __uint_as_float(mb[i]);
        float wv = w[i];
        num = wv * mv;
        den = wv;
    }
    for (int off = 32; off > 0; off >>= 1) {
        num += __shfl_down(num, off);
        den += __shfl_down(den, off);
    }
    __shared__ float snum[BLOCK/64], sden[BLOCK/64];
    int wid = threadIdx.x >> 6, lane = threadIdx.x & 63;
    if (lane == 0) { snum[wid] = num; sden[wid] = den; }
    __syncthreads();
    if (threadIdx.x == 0) {
        float tn = 0.0f, td = 0.0f;
        #pragma unroll
        for (int k = 0; k < BLOCK/64; ++k) { tn += snum[k]; td += sden[k]; }
        atomicAdd(&acc[0], tn);
        atomicAdd(&acc[1], td);
    }
}

__global__ void finalize_kernel(const float* __restrict__ accum,
                                float* __restrict__ out)
{
    out[0] = accum[0] / fmaxf(accum[1], 1e-9f)
           + accum[2] / fmaxf(accum[3], 1e-9f);
}

// ---------------------------------------------------------------------------
extern "C" void kernel_launch(void* const* d_in, const int* in_sizes, int n_in,
                              void* d_out, int out_size, void* d_ws, size_t ws_size,
                              hipStream_t stream)
{
    const float* pred  = (const float*)d_in[0];   // (P,3)
    const float* gt    = (const float*)d_in[1];   // (G,3)
    const float* wpred = (const float*)d_in[2];   // (P,)
    const float* wgt   = (const float*)d_in[3];   // (G,)
    float* out = (float*)d_out;

    // ws layout: packP | packG | minP | minG | accum[4]   (~660 KB)
    float4* packP = (float4*)d_ws;
    float4* packG = packP + NPTS;
    unsigned int* minP = (unsigned int*)(packG + NPTS);
    unsigned int* minG = minP + NPTS;
    float* accum = (float*)(minG + NPTS);

    pack_init_kernel<<<NPTS / BLOCK, BLOCK, 0, stream>>>(
        pred, gt, packP, packG, minP, minG, accum);

    dim3 grid(XBLK, SPLIT, 2);   // 8 x 64 x 2 = 1024 blocks
    min_dist_kernel<<<grid, BLOCK, 0, stream>>>(packP, packG, minP, minG);

    weighted_sum_kernel<<<dim3(NPTS / BLOCK, 2), BLOCK, 0, stream>>>(
        minP, minG, wpred, wgt, accum);

    finalize_kernel<<<1, 1, 0, stream>>>(accum, out);
}